// Round 10
// baseline (718.048 us; speedup 1.0000x reference)
//
#include <hip/hip_runtime.h>
#include <hip/hip_fp16.h>
#include <math.h>

#define SD 10
#define BSZ 64                // round-kernel bucket (nodes per round block)
#define EB 256                // edge-chunk blocks (pass-1 grid): <=32/XCD resident
#define CTHR 1024             // threads for pass1/pass2
#define BINB 8                // bin bits: 256 nodes per bin (bin fits one LDS stage)
#define NBIN_MAX 1024         // N <= 1024*256 = 262144 (and N < 2^18 gate)
#define SCAP 10880            // LDS staging capacity (records); mean bin = 8192
#define QSPLIT 4              // pass-1 sequential quarter-scatters (frontier /4)

typedef unsigned uvec4 __attribute__((ext_vector_type(4)));
struct rec12 { unsigned x, y, z; };   // 12B packed payload
union U32H2 { unsigned u; __half2 h; };

__device__ __forceinline__ float tanh_fast(float x) {
    float e = __expf(2.0f * x);
    float r = __builtin_amdgcn_rcpf(1.0f + e);
    return 1.0f - 2.0f * r;
}

__device__ __forceinline__ float softplus_f(float x) {
    return fmaxf(x, 0.0f) + log1pf(expf(-fabsf(x)));
}

// ===================== prep =====================

// coords4[n] = {x, y, z, g1=|x|+|y|+|z|}: g1 rides along with every cf gather.
__global__ __launch_bounds__(256) void coords4_kernel(
    const float* __restrict__ coords, float4* __restrict__ coords4, int N)
{
    int n = blockIdx.x * blockDim.x + threadIdx.x;
    if (n >= N) return;
    float4 c;
    c.x = coords[n * 3 + 0];
    c.y = coords[n * 3 + 1];
    c.z = coords[n * 3 + 2];
    c.w = fabsf(c.x) + fabsf(c.y) + fabsf(c.z);
    coords4[n] = c;
}

// ===================== build: 2-pass radix with full nt-sort =====================
// Frontier invariant: partial 128B write lines alive at once must fit WELL inside
// L2 (r9 showed 3.2MB marginal -> 3.2x write amp). pass1 therefore scatters in
// QSPLIT sequential quarter-passes over disjoint bin ranges: frontier = 32
// resident blocks x ~196 bins x 128B = 0.8MB. nto is re-scanned per quarter
// (L3-served); each edge's feature words are loaded once, in its own quarter.
// pass2: one bin = one LDS stage; sorted output streams out as FULL lines.

// Pass 1: block b splits its chunk [ebeg,eend) by 256-node bin, contiguous emit.
// Record: x = nf | (nt&255)<<18 ; y = h2(elen, ev0) ; z = h2(ev1, ev2).
// Emits s1addr[bin][b] = segment start; sentinel row s1addr[NBIN][b] = chunk end.
__global__ __launch_bounds__(CTHR) void pass1_kernel(
    const float* __restrict__ elen,
    const float* __restrict__ evec,
    const int* __restrict__ nfrom,
    const int* __restrict__ nto,
    unsigned* __restrict__ s1addr,
    rec12* __restrict__ payA,
    int E, int NBIN)
{
    __shared__ unsigned hbin[NBIN_MAX];   // 4 KB
    __shared__ unsigned curbin[NBIN_MAX]; // 4 KB
    int b = blockIdx.x, t = threadIdx.x;
    long long ebeg = (long long)E * b / EB;
    long long eend = (long long)E * (b + 1) / EB;

    hbin[t] = 0;
    __syncthreads();
    for (long long e = ebeg + t; e < eend; e += CTHR)
        atomicAdd(&hbin[((unsigned)__builtin_nontemporal_load(&nto[e])) >> BINB], 1u);
    __syncthreads();
    {   // exclusive scan of hbin -> curbin (1024 lanes)
        unsigned v = hbin[t];
        for (int d = 1; d < NBIN_MAX; d <<= 1) {
            unsigned x = (t >= d) ? hbin[t - d] : 0u;
            __syncthreads();
            hbin[t] += x;
            __syncthreads();
        }
        curbin[t] = (unsigned)ebeg + hbin[t] - v;
    }
    __syncthreads();
    if (t < NBIN) s1addr[(size_t)t * EB + b] = curbin[t];
    if (t == 0)  s1addr[(size_t)NBIN * EB + b] = (unsigned)eend;
    __syncthreads();

    // QSPLIT sequential quarter-scatters over disjoint bin ranges. No barriers
    // needed between quarters: bins/cursors/output ranges are disjoint, so final
    // positions are identical to a single-pass scatter.
    unsigned QW = ((unsigned)NBIN + QSPLIT - 1u) / QSPLIT;
    for (int h = 0; h < QSPLIT; ++h) {
        unsigned qlo = (unsigned)h * QW;
        unsigned qhi = qlo + QW;
        for (long long e = ebeg + t; e < eend; e += CTHR) {
            int nt = __builtin_nontemporal_load(&nto[e]);
            unsigned bin = ((unsigned)nt) >> BINB;
            if (bin < qlo || bin >= qhi) continue;
            int nf = __builtin_nontemporal_load(&nfrom[e]);
            float l  = __builtin_nontemporal_load(&elen[e]);
            float ex = __builtin_nontemporal_load(&evec[e * 3 + 0]);
            float ey = __builtin_nontemporal_load(&evec[e * 3 + 1]);
            float ez = __builtin_nontemporal_load(&evec[e * 3 + 2]);
            unsigned pos = atomicAdd(&curbin[bin], 1u);
            U32H2 a, c;
            a.h = __floats2half2_rn(l, ex);
            c.h = __floats2half2_rn(ey, ez);
            rec12 r;
            r.x = (unsigned)nf | (((unsigned)nt & ((1u << BINB) - 1u)) << 18);
            r.y = a.u;
            r.z = c.u;
            payA[pos] = r;
        }
    }
}

// Column sums of s1addr rows -> binsum[q] (q = 0..NBIN). EB==256, 256 thr: 1 each.
__global__ __launch_bounds__(256) void colsum_kernel(
    const unsigned* __restrict__ s1addr, unsigned* __restrict__ binsum)
{
    __shared__ unsigned red[256];
    int q = blockIdx.x, t = threadIdx.x;
    red[t] = s1addr[(size_t)q * EB + t];
    __syncthreads();
    for (int d = 128; d > 0; d >>= 1) {
        if (t < d) red[t] += red[t + d];
        __syncthreads();
    }
    if (t == 0) binsum[q] = red[0];
}

// binstart[q] = binsum[q] - binsum[0]  (since s1addr[0][b] = chunk start).
// Also writes the nodestart sentinel at NBIN<<BINB.
__global__ __launch_bounds__(256) void binstart_kernel(
    const unsigned* __restrict__ binsum, unsigned* __restrict__ binstart,
    unsigned* __restrict__ nodestart, int NBIN, int E)
{
    int t = threadIdx.x;
    unsigned b0 = binsum[0];
    for (int q = t; q <= NBIN; q += 256) binstart[q] = binsum[q] - b0;
    if (t == 0) nodestart[(size_t)NBIN << BINB] = (unsigned)E;
}

// Pass 2: one block per bin (256 nodes). Histogram scan (warms L2) -> key scan ->
// cursors + node CSR. Then ONE staged pass: re-scan the bin (L2-hit), scatter all
// records into the 130KB LDS stage via LDS cursors, barrier, stream LDS -> dst as
// contiguous FULL-LINE writes, computing features during streamout (ct gather is
// nt-sorted -> L1; cf gather hidden by a 2-deep pipeline). Oversized bins
// (statistically never) fall back to direct scatter -- still correct.
__global__ __launch_bounds__(CTHR) void pass2_kernel(
    const unsigned* __restrict__ s1addr,
    const unsigned* __restrict__ binstart,
    const float4* __restrict__ coords4,
    const rec12* __restrict__ src,
    rec12* __restrict__ dst,
    unsigned* __restrict__ nodestart,
    int NBIN)
{
    __shared__ unsigned segst[EB];          // 1 KB
    __shared__ unsigned spref[EB + 1];      // 1 KB
    __shared__ unsigned hist[1 << BINB];    // 1 KB
    __shared__ unsigned cur[1 << BINB];     // 1 KB
    __shared__ rec12 stage[SCAP];           // 130.6 KB
    int q = blockIdx.x, t = threadIdx.x;
    const unsigned KMASK = (1u << BINB) - 1u;

    if (t < EB) {
        unsigned st = s1addr[(size_t)q * EB + t];
        unsigned en = s1addr[(size_t)(q + 1) * EB + t];
        segst[t] = st;
        spref[t] = en - st;
    }
    if (t < (1 << BINB)) hist[t] = 0;
    __syncthreads();
    {   // exclusive scan of the 256 segment lengths
        unsigned v = (t < EB) ? spref[t] : 0u;
        for (int d = 1; d < EB; d <<= 1) {
            unsigned x = (t < EB && t >= d) ? spref[t - d] : 0u;
            __syncthreads();
            if (t < EB) spref[t] += x;
            __syncthreads();
        }
        unsigned incl = (t < EB) ? spref[t] : 0u;
        __syncthreads();
        if (t < EB) spref[t] = incl - v;
        if (t == EB - 1) spref[EB] = incl;
    }
    __syncthreads();
    unsigned len = spref[EB];
    unsigned obase = binstart[q];
    const unsigned* srcw = (const unsigned*)src;

    // histogram scan (reads word0; pulls whole lines -> warms L2 for the re-scan)
    for (unsigned i = t; i < len; i += CTHR) {
        unsigned lo = 0, hi = EB;
#pragma unroll
        for (int s = 0; s < 8; s++) {       // log2(EB)
            unsigned mid = (lo + hi) >> 1;
            if (spref[mid] <= i) lo = mid; else hi = mid;
        }
        unsigned x0 = srcw[(size_t)(segst[lo] + (i - spref[lo])) * 3];
        atomicAdd(&hist[(x0 >> 18) & KMASK], 1u);
    }
    __syncthreads();
    // exclusive scan of 256-key histogram (lanes t < 256)
    {
        unsigned hv = (t < (1 << BINB)) ? hist[t] : 0u;
        for (int d = 1; d < (1 << BINB); d <<= 1) {
            unsigned x = (t < (1 << BINB) && t >= d) ? hist[t - d] : 0u;
            __syncthreads();
            if (t < (1 << BINB)) hist[t] += x;
            __syncthreads();
        }
        if (t < (1 << BINB)) {
            unsigned excl = hist[t] - hv;
            cur[t] = obase + excl;
            nodestart[((size_t)q << BINB) + t] = obase + excl;   // node-level CSR
        }
    }
    __syncthreads();

    if (len <= (unsigned)SCAP) {
        // single staged pass: scatter into LDS (no global partial lines)
        for (unsigned i = t; i < len; i += CTHR) {
            unsigned lo = 0, hi = EB;
#pragma unroll
            for (int s = 0; s < 8; s++) {
                unsigned mid = (lo + hi) >> 1;
                if (spref[mid] <= i) lo = mid; else hi = mid;
            }
            rec12 p = src[segst[lo] + (i - spref[lo])];
            unsigned pos = atomicAdd(&cur[(p.x >> 18) & KMASK], 1u);
            stage[pos - obase] = p;
        }
        __syncthreads();
        // streamout: full-line contiguous writes; features computed here.
        // 2-deep pipeline hides the random cf gather; ct gather is nt-sorted.
        unsigned i = t;
        rec12 p0; float4 cf0;
        if (i < len) {
            p0 = stage[i];
            cf0 = coords4[p0.x & 0x3FFFFu];
        }
        while (i < len) {
            unsigned i1 = i + CTHR;
            rec12 p1 = p0; float4 cf1 = cf0;
            if (i1 < len) {
                p1 = stage[i1];
                cf1 = coords4[p1.x & 0x3FFFFu];
            }
            unsigned key = (p0.x >> 18) & KMASK;
            unsigned nf = p0.x & 0x3FFFFu;
            unsigned nt = ((unsigned)q << BINB) | key;
            float4 ct = coords4[nt];
            U32H2 ya, za;
            ya.u = p0.y; za.u = p0.z;
            float g0 = __low2float(ya.h), ev0 = __high2float(ya.h);
            float ev1 = __low2float(za.h), ev2 = __high2float(za.h);
            float g2 = cf0.x * ct.x + cf0.y * ct.y + cf0.z * ct.z;
            float g3 = cf0.x * ev0 + cf0.y * ev1 + cf0.z * ev2;
            U32H2 oy, oz;
            oy.h = __floats2half2_rn(g0, cf0.w);
            oz.h = __floats2half2_rn(g2, g3);
            rec12 r;
            r.x = nf | ((nt & (BSZ - 1u)) << 18);
            r.y = oy.u;
            r.z = oz.u;
            dst[obase + i] = r;
            i = i1; p0 = p1; cf0 = cf1;
        }
    } else {
        // fallback: direct scatter (correct, partial-line cost; ~never taken)
        for (unsigned i = t; i < len; i += CTHR) {
            unsigned lo = 0, hi = EB;
#pragma unroll
            for (int s = 0; s < 8; s++) {
                unsigned mid = (lo + hi) >> 1;
                if (spref[mid] <= i) lo = mid; else hi = mid;
            }
            rec12 p = src[segst[lo] + (i - spref[lo])];
            unsigned key = (p.x >> 18) & KMASK;
            unsigned pos = atomicAdd(&cur[key], 1u);
            unsigned nf = p.x & 0x3FFFFu;
            unsigned nt = ((unsigned)q << BINB) | key;
            float4 cf = coords4[nf];
            float4 ct = coords4[nt];
            U32H2 ya, za;
            ya.u = p.y; za.u = p.z;
            float g0 = __low2float(ya.h), ev0 = __high2float(ya.h);
            float ev1 = __low2float(za.h), ev2 = __high2float(za.h);
            float g2 = cf.x * ct.x + cf.y * ct.y + cf.z * ct.z;
            float g3 = cf.x * ev0 + cf.y * ev1 + cf.z * ev2;
            U32H2 oy, oz;
            oy.h = __floats2half2_rn(g0, cf.w);
            oz.h = __floats2half2_rn(g2, g3);
            rec12 r;
            r.x = nf | ((nt & (BSZ - 1u)) << 18);
            r.y = oy.u;
            r.z = oz.u;
            dst[pos] = r;
        }
    }
}

// ===================== rounds =====================

// wsth[n][j] = fp16( bm[j] + sum_k state[n][k] * Wm[k][j] ), dense 20B rows (4MB total)
__global__ __launch_bounds__(256) void wstate_kernel(
    const float* __restrict__ state, const float* __restrict__ Wm,
    const float* __restrict__ bm, __half* __restrict__ wsth, int N)
{
    int n = blockIdx.x * blockDim.x + threadIdx.x;
    if (n >= N) return;
    const float2* sp = (const float2*)(state + (size_t)n * SD);
    float s[SD];
#pragma unroll
    for (int h = 0; h < 5; h++) { float2 v = sp[h]; s[2*h] = v.x; s[2*h+1] = v.y; }
    float t[SD];
#pragma unroll
    for (int j = 0; j < SD; j++) t[j] = bm[j];
#pragma unroll
    for (int k = 0; k < SD; k++) {
#pragma unroll
        for (int j = 0; j < SD; j++) t[j] += s[k] * Wm[k * SD + j];
    }
    unsigned* dp = (unsigned*)(wsth + (size_t)n * SD);   // 20B rows, 4B aligned
#pragma unroll
    for (int h = 0; h < 5; h++) {
        U32H2 cv;
        cv.h = __floats2half2_rn(t[2*h], t[2*h+1]);
        dp[h] = cv.u;
    }
}

// Run-accumulating round kernel: BSZ=64 -> grid ~3125, high occupancy. Payload
// FULLY nt-sorted (runs ~32/node) -> LDS atomic only on run change. 12B records.
template <bool FIRST>
__global__ __launch_bounds__(256) void round_run_kernel(
    const unsigned* __restrict__ nodestart,
    const rec12* __restrict__ payload,
    const float* __restrict__ Wm,
    const float* __restrict__ bm,
    const __half* __restrict__ wsth,      // (N,10) dense fp16, incl bias
    const float* __restrict__ state_prev,
    float* __restrict__ state_next,
    int N, int E)
{
    __shared__ float acc[BSZ * SD];       // 2.56 KB
    int k = blockIdx.x;
    for (int i = threadIdx.x; i < BSZ * SD; i += 256) acc[i] = 0.0f;

    int lane = threadIdx.x & 63;
    int wv = threadIdx.x >> 6;            // 0..3
    int grp0 = lane / 10;
    bool active = grp0 < 6;
    int grp = active ? grp0 : 5;
    int j = active ? (lane - grp0 * 10) : (lane - 60);

    float w0 = Wm[10 * SD + j];
    float w1 = Wm[11 * SD + j];
    float w2 = Wm[12 * SD + j];
    float w3 = Wm[13 * SD + j];
    float bb = bm[j];
    __syncthreads();

    unsigned beg = nodestart[(size_t)k << 6];
    unsigned end = nodestart[(size_t)(k + 1) << 6];
    unsigned len = end - beg;
    unsigned Q = (len + 3) >> 2;
    unsigned rbeg = beg + (unsigned)wv * Q;
    unsigned rend = rbeg + Q; if (rend > end) rend = end;
    unsigned eclamp = (unsigned)E - 1u;

    // pipeline preload: payload depth 2, wst depth 1
    unsigned e0 = rbeg + (unsigned)grp;
    rec12 P0 = payload[e0 <= eclamp ? e0 : eclamp];
    unsigned e1 = e0 + 6;
    rec12 P1 = payload[e1 <= eclamp ? e1 : eclamp];
    float T0 = bb, T1 = bb;
    if (!FIRST) T0 = __half2float(wsth[(size_t)(P0.x & 0x3FFFFu) * SD + j]);

    int cur_lnt = -1;
    float accv = 0.0f;

    for (unsigned base = rbeg; base < rend; base += 6) {
        unsigned e2 = base + 12 + (unsigned)grp;
        rec12 P2 = payload[e2 <= eclamp ? e2 : eclamp];
        if (!FIRST) T1 = __half2float(wsth[(size_t)(P1.x & 0x3FFFFu) * SD + j]);
        unsigned e = base + (unsigned)grp;
        if (active && e < rend) {
            int lnt = (int)((P0.x >> 18) & (BSZ - 1));
            U32H2 c01, c23;
            c01.u = P0.y; c23.u = P0.z;
            float g0 = __low2float(c01.h), g1 = __high2float(c01.h);
            float g2 = __low2float(c23.h), g3 = __high2float(c23.h);
            float t = T0 + g0 * w0 + g1 * w1 + g2 * w2 + g3 * w3;
            if (lnt != cur_lnt) {
                if (cur_lnt >= 0) atomicAdd(&acc[cur_lnt * SD + j], accv);
                accv = 0.0f;
                cur_lnt = lnt;
            }
            accv += tanh_fast(t);
        }
        P0 = P1; P1 = P2; T0 = T1;
    }
    if (active && cur_lnt >= 0) atomicAdd(&acc[cur_lnt * SD + j], accv);
    __syncthreads();

    int base_o = k * BSZ * SD;
    int lim = N * SD - base_o;
    for (int i = threadIdx.x; i < BSZ * SD; i += 256) {
        if (i < lim) {
            float v = acc[i];
            if (!FIRST) v += state_prev[base_o + i];
            state_next[base_o + i] = v;
        }
    }
}

// ===================== graph phase =====================

__global__ __launch_bounds__(256) void goff_kernel(
    const int* __restrict__ gidx, unsigned* __restrict__ goff, int N, int G)
{
    int n = blockIdx.x * blockDim.x + threadIdx.x;
    if (n >= N) return;
    int g = gidx[n];
    if (n == 0) {
        for (int q = 0; q <= g; q++) goff[q] = 0;
    } else {
        int gp = gidx[n - 1];
        for (int q = gp + 1; q <= g; q++) goff[q] = (unsigned)n;
    }
    if (n == N - 1) {
        for (int q = g + 1; q <= G; q++) goff[q] = (unsigned)N;
    }
}

// 4-way split per (g,j); one atomic per partial. gstate must be zeroed.
__global__ __launch_bounds__(256) void gsum_kernel(
    const float* __restrict__ state, const unsigned* __restrict__ goff,
    float* __restrict__ gstate, int G)
{
    int tid = blockIdx.x * blockDim.x + threadIdx.x;
    if (tid >= G * SD * 4) return;
    int s = tid & 3;
    int rest = tid >> 2;
    int g = rest / SD;
    int j = rest - g * SD;
    unsigned beg = goff[g], end = goff[g + 1];
    unsigned len = end - beg;
    unsigned b0 = beg + (len * (unsigned)s) / 4u;
    unsigned b1 = beg + (len * (unsigned)(s + 1)) / 4u;
    float a = 0.0f;
    for (unsigned n = b0; n < b1; n++) a += state[(size_t)n * SD + j];
    atomicAdd(&gstate[(size_t)g * SD + j], a);
}

__global__ __launch_bounds__(256) void out_kernel(
    const float* __restrict__ gstate, const float* __restrict__ Wo,
    const float* __restrict__ bo, float* __restrict__ out, int G)
{
    int g = blockIdx.x * blockDim.x + threadIdx.x;
    if (g >= G) return;
    float s[SD];
#pragma unroll
    for (int k = 0; k < SD; k++) s[k] = gstate[(size_t)g * SD + k];
    float ev[4];
#pragma unroll
    for (int c = 0; c < 4; c++) {
        float a = bo[c];
#pragma unroll
        for (int k = 0; k < SD; k++) a += s[k] * Wo[k * 4 + c];
        ev[c] = a;
    }
    out[g * 4 + 0] = ev[0];
    out[g * 4 + 1] = softplus_f(ev[1]);
    out[g * 4 + 2] = softplus_f(ev[2]) + 1.0f;
    out[g * 4 + 3] = softplus_f(ev[3]);
}

// ===================== fallback (atomic path) =====================

template <bool FIRST>
__global__ __launch_bounds__(256) void edge_kernel_fb(
    const float* __restrict__ coords, const float* __restrict__ elen,
    const float* __restrict__ evec, const float* __restrict__ Wm,
    const float* __restrict__ bm, const int* __restrict__ nfrom,
    const int* __restrict__ nto, const float* __restrict__ state_prev,
    float* __restrict__ state_next, int E)
{
    int e = blockIdx.x * blockDim.x + threadIdx.x;
    if (e >= E) return;
    int nf = nfrom[e];
    int nt = nto[e];
    float cf0 = coords[nf*3+0], cf1 = coords[nf*3+1], cf2 = coords[nf*3+2];
    float ct0 = coords[nt*3+0], ct1 = coords[nt*3+1], ct2 = coords[nt*3+2];
    float ev0 = evec[e*3+0], ev1 = evec[e*3+1], ev2 = evec[e*3+2];
    float g0 = elen[e];
    float g1 = fabsf(cf0) + fabsf(cf1) + fabsf(cf2);
    float g2 = cf0*ct0 + cf1*ct1 + cf2*ct2;
    float g3 = cf0*ev0 + cf1*ev1 + cf2*ev2;
    float acc[SD];
#pragma unroll
    for (int j = 0; j < SD; j++) {
        acc[j] = bm[j] + g0*Wm[10*SD+j] + g1*Wm[11*SD+j] + g2*Wm[12*SD+j] + g3*Wm[13*SD+j];
    }
    if (!FIRST) {
        const float2* sp = (const float2*)(state_prev + (size_t)nf * SD);
        float s[SD];
#pragma unroll
        for (int h = 0; h < 5; h++) { float2 v = sp[h]; s[2*h] = v.x; s[2*h+1] = v.y; }
#pragma unroll
        for (int k = 0; k < SD; k++) {
#pragma unroll
            for (int j = 0; j < SD; j++) acc[j] += s[k] * Wm[k*SD+j];
        }
    }
    float* dst = state_next + (size_t)nt * SD;
#pragma unroll
    for (int j = 0; j < SD; j++) atomicAdd(dst + j, tanh_fast(acc[j]));
}

__global__ __launch_bounds__(256) void graph_reduce_fb(
    const float* __restrict__ state, const int* __restrict__ gidx,
    float* __restrict__ gstate, int N)
{
    int n = blockIdx.x * blockDim.x + threadIdx.x;
    if (n >= N) return;
    int g = gidx[n];
    const float2* sp = (const float2*)(state + (size_t)n * SD);
    float* dst = gstate + (size_t)g * SD;
#pragma unroll
    for (int h = 0; h < 5; h++) {
        float2 v = sp[h];
        atomicAdd(dst + 2*h, v.x);
        atomicAdd(dst + 2*h + 1, v.y);
    }
}

// ===================== launch =====================

extern "C" void kernel_launch(void* const* d_in, const int* in_sizes, int n_in,
                              void* d_out, int out_size, void* d_ws, size_t ws_size,
                              hipStream_t stream) {
    const float* coords = (const float*)d_in[0];
    const float* elen   = (const float*)d_in[1];
    const float* evec   = (const float*)d_in[2];
    const float* Wm     = (const float*)d_in[3];
    const float* bm     = (const float*)d_in[4];
    const float* Wo     = (const float*)d_in[5];
    const float* bo     = (const float*)d_in[6];
    const int* nfrom    = (const int*)d_in[7];
    const int* nto      = (const int*)d_in[8];
    const int* gidx     = (const int*)d_in[9];

    const int E = in_sizes[1];
    const int N = in_sizes[9];
    const int G = out_size / 4;

    const int NBIN = (N + (1 << BINB) - 1) >> BINB;   // bins (<= 1024)
    const int NB   = (N + BSZ - 1) / BSZ;             // round buckets (~3125)

    const int BLK = 256;
    const int ng = (N + BLK - 1) / BLK;
    const int gg = (G + BLK - 1) / BLK;

    auto align256 = [](size_t x) { return (x + 255) & ~(size_t)255; };
    const size_t state_bytes = align256((size_t)N * SD * sizeof(float));
    const size_t wst_bytes   = align256((size_t)N * SD * sizeof(__half) + 256);
    const size_t payA_bytes  = align256((size_t)E * sizeof(rec12) + 256);
    const size_t payB_bytes  = align256((size_t)E * sizeof(rec12) + 256);
    const size_t s1a_bytes   = align256((size_t)(NBIN_MAX + 1) * EB * sizeof(unsigned));
    const size_t bsum_bytes  = align256((size_t)(NBIN_MAX + 1) * sizeof(unsigned));
    const size_t nst_bytes   = align256(((size_t)NBIN_MAX * (1 << BINB) + 2) * sizeof(unsigned));
    const size_t goff_bytes  = align256((size_t)(G + 1) * sizeof(unsigned));
    const size_t gst_bytes   = align256((size_t)G * SD * sizeof(float));
    const size_t c4_bytes    = align256((size_t)N * sizeof(float4));

    size_t o = 0;
    char* w = (char*)d_ws;
    float* stateA      = (float*)(w + o);    o += state_bytes;
    float* stateB      = (float*)(w + o);    o += state_bytes;
    __half* wsth       = (__half*)(w + o);   o += wst_bytes;
    rec12* payA        = (rec12*)(w + o);    o += payA_bytes;   // bin-sorted block-major
    rec12* payB        = (rec12*)(w + o);    o += payB_bytes;   // fully nt-sorted
    unsigned* s1addr   = (unsigned*)(w + o); o += s1a_bytes;
    unsigned* binsum   = (unsigned*)(w + o); o += bsum_bytes;
    unsigned* binstart = (unsigned*)(w + o); o += bsum_bytes;
    unsigned* nodestart= (unsigned*)(w + o); o += nst_bytes;
    unsigned* goff     = (unsigned*)(w + o); o += goff_bytes;
    float* gstate      = (float*)(w + o);    o += gst_bytes;
    float4* coords4    = (float4*)(w + o);   o += c4_bytes;

    if (o <= ws_size && NBIN <= NBIN_MAX && N < (1 << 18)) {
        // ---- prep + build ----
        coords4_kernel<<<ng, BLK, 0, stream>>>(coords, coords4, N);
        pass1_kernel<<<EB, CTHR, 0, stream>>>(elen, evec, nfrom, nto,
                                              s1addr, payA, E, NBIN);
        colsum_kernel<<<NBIN + 1, 256, 0, stream>>>(s1addr, binsum);
        binstart_kernel<<<1, 256, 0, stream>>>(binsum, binstart, nodestart, NBIN, E);
        pass2_kernel<<<NBIN, CTHR, 0, stream>>>(s1addr, binstart, coords4,
                                                payA, payB, nodestart, NBIN);
        // ---- rounds (sorted 12B payload, high-occupancy 64-node buckets) ----
        round_run_kernel<true><<<NB, BLK, 0, stream>>>(nodestart, payB, Wm, bm,
                                                       wsth, stateB, stateA, N, E);
        wstate_kernel<<<ng, BLK, 0, stream>>>(stateA, Wm, bm, wsth, N);
        round_run_kernel<false><<<NB, BLK, 0, stream>>>(nodestart, payB, Wm, bm,
                                                        wsth, stateA, stateB, N, E);
        wstate_kernel<<<ng, BLK, 0, stream>>>(stateB, Wm, bm, wsth, N);
        round_run_kernel<false><<<NB, BLK, 0, stream>>>(nodestart, payB, Wm, bm,
                                                        wsth, stateB, stateA, N, E);
        // ---- graph phase ----
        hipMemsetAsync(gstate, 0, (size_t)G * SD * sizeof(float), stream);
        goff_kernel<<<ng, BLK, 0, stream>>>(gidx, goff, N, G);
        gsum_kernel<<<(G * SD * 4 + BLK - 1) / BLK, BLK, 0, stream>>>(stateA, goff, gstate, G);
        out_kernel<<<gg, BLK, 0, stream>>>(gstate, Wo, bo, (float*)d_out, G);
    } else {
        // ---- fallback: atomic path ----
        const int eg = (E + BLK - 1) / BLK;
        float* gstateF = (float*)(w + 2 * state_bytes);
        hipMemsetAsync(stateA, 0, state_bytes, stream);
        hipMemsetAsync(gstateF, 0, (size_t)G * SD * sizeof(float), stream);
        edge_kernel_fb<true><<<eg, BLK, 0, stream>>>(coords, elen, evec, Wm, bm,
                                                     nfrom, nto, stateA, stateA, E);
        hipMemcpyAsync(stateB, stateA, state_bytes, hipMemcpyDeviceToDevice, stream);
        edge_kernel_fb<false><<<eg, BLK, 0, stream>>>(coords, elen, evec, Wm, bm,
                                                      nfrom, nto, stateA, stateB, E);
        hipMemcpyAsync(stateA, stateB, state_bytes, hipMemcpyDeviceToDevice, stream);
        edge_kernel_fb<false><<<eg, BLK, 0, stream>>>(coords, elen, evec, Wm, bm,
                                                      nfrom, nto, stateB, stateA, E);
        graph_reduce_fb<<<ng, BLK, 0, stream>>>(stateA, gidx, gstateF, N);
        out_kernel<<<gg, BLK, 0, stream>>>(gstateF, Wo, bo, (float*)d_out, G);
    }
}

// Round 11
// 692.818 us; speedup vs baseline: 1.0364x; 1.0364x over previous
//
#include <hip/hip_runtime.h>
#include <hip/hip_fp16.h>
#include <math.h>

#define SD 10
#define BSZ 64                // round-kernel bucket (nodes per round block)
#define EB 256                // edge-chunk blocks (pass-1 grid): <=32/XCD resident
#define CTHR 1024             // threads for pass1/pass2
#define BINB 8                // bin bits: 256 nodes per bin (bin fits one LDS stage)
#define NBIN_MAX 1024         // N <= 1024*256 = 262144 (and N < 2^18 gate)
#define SCAP 10880            // pass-2 LDS staging capacity (records); mean bin = 8192
#define QSPLIT 4              // pass-1 sequential quarter-scatters (frontier /4)
#define ECHUNK 25600          // pass-1 per-block edge-chunk capacity (LDS stash)

typedef unsigned uvec4 __attribute__((ext_vector_type(4)));
struct rec12 { unsigned x, y, z; };   // 12B packed payload
union U32H2 { unsigned u; __half2 h; };

__device__ __forceinline__ float tanh_fast(float x) {
    float e = __expf(2.0f * x);
    float r = __builtin_amdgcn_rcpf(1.0f + e);
    return 1.0f - 2.0f * r;
}

__device__ __forceinline__ float softplus_f(float x) {
    return fmaxf(x, 0.0f) + log1pf(expf(-fabsf(x)));
}

// ===================== prep =====================

// coords4[n] = {x, y, z, g1=|x|+|y|+|z|}: g1 rides along with every cf gather.
__global__ __launch_bounds__(256) void coords4_kernel(
    const float* __restrict__ coords, float4* __restrict__ coords4, int N)
{
    int n = blockIdx.x * blockDim.x + threadIdx.x;
    if (n >= N) return;
    float4 c;
    c.x = coords[n * 3 + 0];
    c.y = coords[n * 3 + 1];
    c.z = coords[n * 3 + 2];
    c.w = fabsf(c.x) + fabsf(c.y) + fabsf(c.z);
    coords4[n] = c;
}

// ===================== build: 2-pass radix with full nt-sort =====================
// Frontier invariant: partial 128B write lines alive at once must fit WELL inside
// L2 (r9: 3.2MB marginal -> 3.2x write amp; r10 quartering fixed writes 244->106MB).
// r10 lesson: quartering must NOT re-read inputs with NT loads (NT blocks the
// cross-quarter line reuse -> FETCH 326MB). v3: bin keys are stashed in LDS during
// the histogram scan (nto read ONCE, NT); quarter-scatters read keys from LDS and
// load features with CACHED loads (L2/L3 absorbs the 1/4-density line sharing).

// Pass 1: block b splits its chunk [ebeg,eend) by 256-node bin, contiguous emit.
// Record: x = nf | (nt&255)<<18 ; y = h2(elen, ev0) ; z = h2(ev1, ev2).
// Emits s1addr[bin][b] = segment start; sentinel row s1addr[NBIN][b] = chunk end.
__global__ __launch_bounds__(CTHR) void pass1_kernel(
    const float* __restrict__ elen,
    const float* __restrict__ evec,
    const int* __restrict__ nfrom,
    const int* __restrict__ nto,
    unsigned* __restrict__ s1addr,
    rec12* __restrict__ payA,
    int E, int NBIN)
{
    __shared__ unsigned hbin[NBIN_MAX];        // 4 KB
    __shared__ unsigned curbin[NBIN_MAX];      // 4 KB
    __shared__ unsigned short sbin[ECHUNK];    // 51.2 KB: per-edge bin
    __shared__ unsigned char  slow[ECHUNK];    // 25.6 KB: per-edge nt&255
    int b = blockIdx.x, t = threadIdx.x;
    long long ebeg = (long long)E * b / EB;
    long long eend = (long long)E * (b + 1) / EB;
    int len = (int)(eend - ebeg);              // <= ECHUNK (launcher gate)

    hbin[t] = 0;
    __syncthreads();
    // single nto scan (NT: read exactly once, keep L2 clean): histogram + stash
    for (int i = t; i < len; i += CTHR) {
        unsigned nt = (unsigned)__builtin_nontemporal_load(&nto[ebeg + i]);
        unsigned bin = nt >> BINB;
        sbin[i] = (unsigned short)bin;
        slow[i] = (unsigned char)(nt & 255u);
        atomicAdd(&hbin[bin], 1u);
    }
    __syncthreads();
    {   // exclusive scan of hbin -> curbin (1024 lanes)
        unsigned v = hbin[t];
        for (int d = 1; d < NBIN_MAX; d <<= 1) {
            unsigned x = (t >= d) ? hbin[t - d] : 0u;
            __syncthreads();
            hbin[t] += x;
            __syncthreads();
        }
        curbin[t] = (unsigned)ebeg + hbin[t] - v;
    }
    __syncthreads();
    if (t < NBIN) s1addr[(size_t)t * EB + b] = curbin[t];
    if (t == 0)  s1addr[(size_t)NBIN * EB + b] = (unsigned)eend;
    __syncthreads();

    // QSPLIT sequential quarter-scatters over disjoint bin ranges (frontier
    // = 32 resident blocks x ~196 bins x 128B = 0.8MB << L2). Keys come from
    // LDS (no global re-scan); feature loads are CACHED so the 1/4-density
    // line sharing across quarters is served by L2/L3, not HBM.
    unsigned QW = ((unsigned)NBIN + QSPLIT - 1u) / QSPLIT;
    for (int h = 0; h < QSPLIT; ++h) {
        unsigned qlo = (unsigned)h * QW;
        unsigned qhi = qlo + QW;
        for (int i = t; i < len; i += CTHR) {
            unsigned bin = sbin[i];
            if (bin < qlo || bin >= qhi) continue;
            long long e = ebeg + i;
            int nf = nfrom[e];
            float l  = elen[e];
            float ex = evec[e * 3 + 0];
            float ey = evec[e * 3 + 1];
            float ez = evec[e * 3 + 2];
            unsigned pos = atomicAdd(&curbin[bin], 1u);
            U32H2 a, c;
            a.h = __floats2half2_rn(l, ex);
            c.h = __floats2half2_rn(ey, ez);
            rec12 r;
            r.x = (unsigned)nf | ((unsigned)slow[i] << 18);
            r.y = a.u;
            r.z = c.u;
            payA[pos] = r;
        }
    }
}

// Column sums of s1addr rows -> binsum[q] (q = 0..NBIN). EB==256, 256 thr: 1 each.
__global__ __launch_bounds__(256) void colsum_kernel(
    const unsigned* __restrict__ s1addr, unsigned* __restrict__ binsum)
{
    __shared__ unsigned red[256];
    int q = blockIdx.x, t = threadIdx.x;
    red[t] = s1addr[(size_t)q * EB + t];
    __syncthreads();
    for (int d = 128; d > 0; d >>= 1) {
        if (t < d) red[t] += red[t + d];
        __syncthreads();
    }
    if (t == 0) binsum[q] = red[0];
}

// binstart[q] = binsum[q] - binsum[0]  (since s1addr[0][b] = chunk start).
// Also writes the nodestart sentinel at NBIN<<BINB.
__global__ __launch_bounds__(256) void binstart_kernel(
    const unsigned* __restrict__ binsum, unsigned* __restrict__ binstart,
    unsigned* __restrict__ nodestart, int NBIN, int E)
{
    int t = threadIdx.x;
    unsigned b0 = binsum[0];
    for (int q = t; q <= NBIN; q += 256) binstart[q] = binsum[q] - b0;
    if (t == 0) nodestart[(size_t)NBIN << BINB] = (unsigned)E;
}

// Pass 2: one block per bin (256 nodes). Histogram scan (warms L2) -> key scan ->
// cursors + node CSR. Then ONE staged pass: re-scan the bin (L2-hit), scatter all
// records into the 130KB LDS stage via LDS cursors, barrier, stream LDS -> dst as
// contiguous FULL-LINE writes, computing features during streamout (ct gather is
// nt-sorted -> L1; cf gather hidden by a 2-deep pipeline). Oversized bins
// (statistically never) fall back to direct scatter -- still correct.
__global__ __launch_bounds__(CTHR) void pass2_kernel(
    const unsigned* __restrict__ s1addr,
    const unsigned* __restrict__ binstart,
    const float4* __restrict__ coords4,
    const rec12* __restrict__ src,
    rec12* __restrict__ dst,
    unsigned* __restrict__ nodestart,
    int NBIN)
{
    __shared__ unsigned segst[EB];          // 1 KB
    __shared__ unsigned spref[EB + 1];      // 1 KB
    __shared__ unsigned hist[1 << BINB];    // 1 KB
    __shared__ unsigned cur[1 << BINB];     // 1 KB
    __shared__ rec12 stage[SCAP];           // 130.6 KB
    int q = blockIdx.x, t = threadIdx.x;
    const unsigned KMASK = (1u << BINB) - 1u;

    if (t < EB) {
        unsigned st = s1addr[(size_t)q * EB + t];
        unsigned en = s1addr[(size_t)(q + 1) * EB + t];
        segst[t] = st;
        spref[t] = en - st;
    }
    if (t < (1 << BINB)) hist[t] = 0;
    __syncthreads();
    {   // exclusive scan of the 256 segment lengths
        unsigned v = (t < EB) ? spref[t] : 0u;
        for (int d = 1; d < EB; d <<= 1) {
            unsigned x = (t < EB && t >= d) ? spref[t - d] : 0u;
            __syncthreads();
            if (t < EB) spref[t] += x;
            __syncthreads();
        }
        unsigned incl = (t < EB) ? spref[t] : 0u;
        __syncthreads();
        if (t < EB) spref[t] = incl - v;
        if (t == EB - 1) spref[EB] = incl;
    }
    __syncthreads();
    unsigned len = spref[EB];
    unsigned obase = binstart[q];
    const unsigned* srcw = (const unsigned*)src;

    // histogram scan (reads word0; pulls whole lines -> warms L2 for the re-scan)
    for (unsigned i = t; i < len; i += CTHR) {
        unsigned lo = 0, hi = EB;
#pragma unroll
        for (int s = 0; s < 8; s++) {       // log2(EB)
            unsigned mid = (lo + hi) >> 1;
            if (spref[mid] <= i) lo = mid; else hi = mid;
        }
        unsigned x0 = srcw[(size_t)(segst[lo] + (i - spref[lo])) * 3];
        atomicAdd(&hist[(x0 >> 18) & KMASK], 1u);
    }
    __syncthreads();
    // exclusive scan of 256-key histogram (lanes t < 256)
    {
        unsigned hv = (t < (1 << BINB)) ? hist[t] : 0u;
        for (int d = 1; d < (1 << BINB); d <<= 1) {
            unsigned x = (t < (1 << BINB) && t >= d) ? hist[t - d] : 0u;
            __syncthreads();
            if (t < (1 << BINB)) hist[t] += x;
            __syncthreads();
        }
        if (t < (1 << BINB)) {
            unsigned excl = hist[t] - hv;
            cur[t] = obase + excl;
            nodestart[((size_t)q << BINB) + t] = obase + excl;   // node-level CSR
        }
    }
    __syncthreads();

    if (len <= (unsigned)SCAP) {
        // single staged pass: scatter into LDS (no global partial lines)
        for (unsigned i = t; i < len; i += CTHR) {
            unsigned lo = 0, hi = EB;
#pragma unroll
            for (int s = 0; s < 8; s++) {
                unsigned mid = (lo + hi) >> 1;
                if (spref[mid] <= i) lo = mid; else hi = mid;
            }
            rec12 p = src[segst[lo] + (i - spref[lo])];
            unsigned pos = atomicAdd(&cur[(p.x >> 18) & KMASK], 1u);
            stage[pos - obase] = p;
        }
        __syncthreads();
        // streamout: full-line contiguous writes; features computed here.
        // 2-deep pipeline hides the random cf gather; ct gather is nt-sorted.
        unsigned i = t;
        rec12 p0; float4 cf0;
        if (i < len) {
            p0 = stage[i];
            cf0 = coords4[p0.x & 0x3FFFFu];
        }
        while (i < len) {
            unsigned i1 = i + CTHR;
            rec12 p1 = p0; float4 cf1 = cf0;
            if (i1 < len) {
                p1 = stage[i1];
                cf1 = coords4[p1.x & 0x3FFFFu];
            }
            unsigned key = (p0.x >> 18) & KMASK;
            unsigned nf = p0.x & 0x3FFFFu;
            unsigned nt = ((unsigned)q << BINB) | key;
            float4 ct = coords4[nt];
            U32H2 ya, za;
            ya.u = p0.y; za.u = p0.z;
            float g0 = __low2float(ya.h), ev0 = __high2float(ya.h);
            float ev1 = __low2float(za.h), ev2 = __high2float(za.h);
            float g2 = cf0.x * ct.x + cf0.y * ct.y + cf0.z * ct.z;
            float g3 = cf0.x * ev0 + cf0.y * ev1 + cf0.z * ev2;
            U32H2 oy, oz;
            oy.h = __floats2half2_rn(g0, cf0.w);
            oz.h = __floats2half2_rn(g2, g3);
            rec12 r;
            r.x = nf | ((nt & (BSZ - 1u)) << 18);
            r.y = oy.u;
            r.z = oz.u;
            dst[obase + i] = r;
            i = i1; p0 = p1; cf0 = cf1;
        }
    } else {
        // fallback: direct scatter (correct, partial-line cost; ~never taken)
        for (unsigned i = t; i < len; i += CTHR) {
            unsigned lo = 0, hi = EB;
#pragma unroll
            for (int s = 0; s < 8; s++) {
                unsigned mid = (lo + hi) >> 1;
                if (spref[mid] <= i) lo = mid; else hi = mid;
            }
            rec12 p = src[segst[lo] + (i - spref[lo])];
            unsigned key = (p.x >> 18) & KMASK;
            unsigned pos = atomicAdd(&cur[key], 1u);
            unsigned nf = p.x & 0x3FFFFu;
            unsigned nt = ((unsigned)q << BINB) | key;
            float4 cf = coords4[nf];
            float4 ct = coords4[nt];
            U32H2 ya, za;
            ya.u = p.y; za.u = p.z;
            float g0 = __low2float(ya.h), ev0 = __high2float(ya.h);
            float ev1 = __low2float(za.h), ev2 = __high2float(za.h);
            float g2 = cf.x * ct.x + cf.y * ct.y + cf.z * ct.z;
            float g3 = cf.x * ev0 + cf.y * ev1 + cf.z * ev2;
            U32H2 oy, oz;
            oy.h = __floats2half2_rn(g0, cf.w);
            oz.h = __floats2half2_rn(g2, g3);
            rec12 r;
            r.x = nf | ((nt & (BSZ - 1u)) << 18);
            r.y = oy.u;
            r.z = oz.u;
            dst[pos] = r;
        }
    }
}

// ===================== rounds =====================

// wsth[n][j] = fp16( bm[j] + sum_k state[n][k] * Wm[k][j] ), dense 20B rows (4MB total)
__global__ __launch_bounds__(256) void wstate_kernel(
    const float* __restrict__ state, const float* __restrict__ Wm,
    const float* __restrict__ bm, __half* __restrict__ wsth, int N)
{
    int n = blockIdx.x * blockDim.x + threadIdx.x;
    if (n >= N) return;
    const float2* sp = (const float2*)(state + (size_t)n * SD);
    float s[SD];
#pragma unroll
    for (int h = 0; h < 5; h++) { float2 v = sp[h]; s[2*h] = v.x; s[2*h+1] = v.y; }
    float t[SD];
#pragma unroll
    for (int j = 0; j < SD; j++) t[j] = bm[j];
#pragma unroll
    for (int k = 0; k < SD; k++) {
#pragma unroll
        for (int j = 0; j < SD; j++) t[j] += s[k] * Wm[k * SD + j];
    }
    unsigned* dp = (unsigned*)(wsth + (size_t)n * SD);   // 20B rows, 4B aligned
#pragma unroll
    for (int h = 0; h < 5; h++) {
        U32H2 cv;
        cv.h = __floats2half2_rn(t[2*h], t[2*h+1]);
        dp[h] = cv.u;
    }
}

// Run-accumulating round kernel: BSZ=64 -> grid ~3125, high occupancy. Payload
// FULLY nt-sorted (runs ~32/node) -> LDS atomic only on run change. 12B records.
template <bool FIRST>
__global__ __launch_bounds__(256) void round_run_kernel(
    const unsigned* __restrict__ nodestart,
    const rec12* __restrict__ payload,
    const float* __restrict__ Wm,
    const float* __restrict__ bm,
    const __half* __restrict__ wsth,      // (N,10) dense fp16, incl bias
    const float* __restrict__ state_prev,
    float* __restrict__ state_next,
    int N, int E)
{
    __shared__ float acc[BSZ * SD];       // 2.56 KB
    int k = blockIdx.x;
    for (int i = threadIdx.x; i < BSZ * SD; i += 256) acc[i] = 0.0f;

    int lane = threadIdx.x & 63;
    int wv = threadIdx.x >> 6;            // 0..3
    int grp0 = lane / 10;
    bool active = grp0 < 6;
    int grp = active ? grp0 : 5;
    int j = active ? (lane - grp0 * 10) : (lane - 60);

    float w0 = Wm[10 * SD + j];
    float w1 = Wm[11 * SD + j];
    float w2 = Wm[12 * SD + j];
    float w3 = Wm[13 * SD + j];
    float bb = bm[j];
    __syncthreads();

    unsigned beg = nodestart[(size_t)k << 6];
    unsigned end = nodestart[(size_t)(k + 1) << 6];
    unsigned len = end - beg;
    unsigned Q = (len + 3) >> 2;
    unsigned rbeg = beg + (unsigned)wv * Q;
    unsigned rend = rbeg + Q; if (rend > end) rend = end;
    unsigned eclamp = (unsigned)E - 1u;

    // pipeline preload: payload depth 2, wst depth 1
    unsigned e0 = rbeg + (unsigned)grp;
    rec12 P0 = payload[e0 <= eclamp ? e0 : eclamp];
    unsigned e1 = e0 + 6;
    rec12 P1 = payload[e1 <= eclamp ? e1 : eclamp];
    float T0 = bb, T1 = bb;
    if (!FIRST) T0 = __half2float(wsth[(size_t)(P0.x & 0x3FFFFu) * SD + j]);

    int cur_lnt = -1;
    float accv = 0.0f;

    for (unsigned base = rbeg; base < rend; base += 6) {
        unsigned e2 = base + 12 + (unsigned)grp;
        rec12 P2 = payload[e2 <= eclamp ? e2 : eclamp];
        if (!FIRST) T1 = __half2float(wsth[(size_t)(P1.x & 0x3FFFFu) * SD + j]);
        unsigned e = base + (unsigned)grp;
        if (active && e < rend) {
            int lnt = (int)((P0.x >> 18) & (BSZ - 1));
            U32H2 c01, c23;
            c01.u = P0.y; c23.u = P0.z;
            float g0 = __low2float(c01.h), g1 = __high2float(c01.h);
            float g2 = __low2float(c23.h), g3 = __high2float(c23.h);
            float t = T0 + g0 * w0 + g1 * w1 + g2 * w2 + g3 * w3;
            if (lnt != cur_lnt) {
                if (cur_lnt >= 0) atomicAdd(&acc[cur_lnt * SD + j], accv);
                accv = 0.0f;
                cur_lnt = lnt;
            }
            accv += tanh_fast(t);
        }
        P0 = P1; P1 = P2; T0 = T1;
    }
    if (active && cur_lnt >= 0) atomicAdd(&acc[cur_lnt * SD + j], accv);
    __syncthreads();

    int base_o = k * BSZ * SD;
    int lim = N * SD - base_o;
    for (int i = threadIdx.x; i < BSZ * SD; i += 256) {
        if (i < lim) {
            float v = acc[i];
            if (!FIRST) v += state_prev[base_o + i];
            state_next[base_o + i] = v;
        }
    }
}

// ===================== graph phase =====================

__global__ __launch_bounds__(256) void goff_kernel(
    const int* __restrict__ gidx, unsigned* __restrict__ goff, int N, int G)
{
    int n = blockIdx.x * blockDim.x + threadIdx.x;
    if (n >= N) return;
    int g = gidx[n];
    if (n == 0) {
        for (int q = 0; q <= g; q++) goff[q] = 0;
    } else {
        int gp = gidx[n - 1];
        for (int q = gp + 1; q <= g; q++) goff[q] = (unsigned)n;
    }
    if (n == N - 1) {
        for (int q = g + 1; q <= G; q++) goff[q] = (unsigned)N;
    }
}

// 4-way split per (g,j); one atomic per partial. gstate must be zeroed.
__global__ __launch_bounds__(256) void gsum_kernel(
    const float* __restrict__ state, const unsigned* __restrict__ goff,
    float* __restrict__ gstate, int G)
{
    int tid = blockIdx.x * blockDim.x + threadIdx.x;
    if (tid >= G * SD * 4) return;
    int s = tid & 3;
    int rest = tid >> 2;
    int g = rest / SD;
    int j = rest - g * SD;
    unsigned beg = goff[g], end = goff[g + 1];
    unsigned len = end - beg;
    unsigned b0 = beg + (len * (unsigned)s) / 4u;
    unsigned b1 = beg + (len * (unsigned)(s + 1)) / 4u;
    float a = 0.0f;
    for (unsigned n = b0; n < b1; n++) a += state[(size_t)n * SD + j];
    atomicAdd(&gstate[(size_t)g * SD + j], a);
}

__global__ __launch_bounds__(256) void out_kernel(
    const float* __restrict__ gstate, const float* __restrict__ Wo,
    const float* __restrict__ bo, float* __restrict__ out, int G)
{
    int g = blockIdx.x * blockDim.x + threadIdx.x;
    if (g >= G) return;
    float s[SD];
#pragma unroll
    for (int k = 0; k < SD; k++) s[k] = gstate[(size_t)g * SD + k];
    float ev[4];
#pragma unroll
    for (int c = 0; c < 4; c++) {
        float a = bo[c];
#pragma unroll
        for (int k = 0; k < SD; k++) a += s[k] * Wo[k * 4 + c];
        ev[c] = a;
    }
    out[g * 4 + 0] = ev[0];
    out[g * 4 + 1] = softplus_f(ev[1]);
    out[g * 4 + 2] = softplus_f(ev[2]) + 1.0f;
    out[g * 4 + 3] = softplus_f(ev[3]);
}

// ===================== fallback (atomic path) =====================

template <bool FIRST>
__global__ __launch_bounds__(256) void edge_kernel_fb(
    const float* __restrict__ coords, const float* __restrict__ elen,
    const float* __restrict__ evec, const float* __restrict__ Wm,
    const float* __restrict__ bm, const int* __restrict__ nfrom,
    const int* __restrict__ nto, const float* __restrict__ state_prev,
    float* __restrict__ state_next, int E)
{
    int e = blockIdx.x * blockDim.x + threadIdx.x;
    if (e >= E) return;
    int nf = nfrom[e];
    int nt = nto[e];
    float cf0 = coords[nf*3+0], cf1 = coords[nf*3+1], cf2 = coords[nf*3+2];
    float ct0 = coords[nt*3+0], ct1 = coords[nt*3+1], ct2 = coords[nt*3+2];
    float ev0 = evec[e*3+0], ev1 = evec[e*3+1], ev2 = evec[e*3+2];
    float g0 = elen[e];
    float g1 = fabsf(cf0) + fabsf(cf1) + fabsf(cf2);
    float g2 = cf0*ct0 + cf1*ct1 + cf2*ct2;
    float g3 = cf0*ev0 + cf1*ev1 + cf2*ev2;
    float acc[SD];
#pragma unroll
    for (int j = 0; j < SD; j++) {
        acc[j] = bm[j] + g0*Wm[10*SD+j] + g1*Wm[11*SD+j] + g2*Wm[12*SD+j] + g3*Wm[13*SD+j];
    }
    if (!FIRST) {
        const float2* sp = (const float2*)(state_prev + (size_t)nf * SD);
        float s[SD];
#pragma unroll
        for (int h = 0; h < 5; h++) { float2 v = sp[h]; s[2*h] = v.x; s[2*h+1] = v.y; }
#pragma unroll
        for (int k = 0; k < SD; k++) {
#pragma unroll
            for (int j = 0; j < SD; j++) acc[j] += s[k] * Wm[k*SD+j];
        }
    }
    float* dst = state_next + (size_t)nt * SD;
#pragma unroll
    for (int j = 0; j < SD; j++) atomicAdd(dst + j, tanh_fast(acc[j]));
}

__global__ __launch_bounds__(256) void graph_reduce_fb(
    const float* __restrict__ state, const int* __restrict__ gidx,
    float* __restrict__ gstate, int N)
{
    int n = blockIdx.x * blockDim.x + threadIdx.x;
    if (n >= N) return;
    int g = gidx[n];
    const float2* sp = (const float2*)(state + (size_t)n * SD);
    float* dst = gstate + (size_t)g * SD;
#pragma unroll
    for (int h = 0; h < 5; h++) {
        float2 v = sp[h];
        atomicAdd(dst + 2*h, v.x);
        atomicAdd(dst + 2*h + 1, v.y);
    }
}

// ===================== launch =====================

extern "C" void kernel_launch(void* const* d_in, const int* in_sizes, int n_in,
                              void* d_out, int out_size, void* d_ws, size_t ws_size,
                              hipStream_t stream) {
    const float* coords = (const float*)d_in[0];
    const float* elen   = (const float*)d_in[1];
    const float* evec   = (const float*)d_in[2];
    const float* Wm     = (const float*)d_in[3];
    const float* bm     = (const float*)d_in[4];
    const float* Wo     = (const float*)d_in[5];
    const float* bo     = (const float*)d_in[6];
    const int* nfrom    = (const int*)d_in[7];
    const int* nto      = (const int*)d_in[8];
    const int* gidx     = (const int*)d_in[9];

    const int E = in_sizes[1];
    const int N = in_sizes[9];
    const int G = out_size / 4;

    const int NBIN = (N + (1 << BINB) - 1) >> BINB;   // bins (<= 1024)
    const int NB   = (N + BSZ - 1) / BSZ;             // round buckets (~3125)
    const int CHUNK = (E + EB - 1) / EB;              // pass-1 chunk size

    const int BLK = 256;
    const int ng = (N + BLK - 1) / BLK;
    const int gg = (G + BLK - 1) / BLK;

    auto align256 = [](size_t x) { return (x + 255) & ~(size_t)255; };
    const size_t state_bytes = align256((size_t)N * SD * sizeof(float));
    const size_t wst_bytes   = align256((size_t)N * SD * sizeof(__half) + 256);
    const size_t payA_bytes  = align256((size_t)E * sizeof(rec12) + 256);
    const size_t payB_bytes  = align256((size_t)E * sizeof(rec12) + 256);
    const size_t s1a_bytes   = align256((size_t)(NBIN_MAX + 1) * EB * sizeof(unsigned));
    const size_t bsum_bytes  = align256((size_t)(NBIN_MAX + 1) * sizeof(unsigned));
    const size_t nst_bytes   = align256(((size_t)NBIN_MAX * (1 << BINB) + 2) * sizeof(unsigned));
    const size_t goff_bytes  = align256((size_t)(G + 1) * sizeof(unsigned));
    const size_t gst_bytes   = align256((size_t)G * SD * sizeof(float));
    const size_t c4_bytes    = align256((size_t)N * sizeof(float4));

    size_t o = 0;
    char* w = (char*)d_ws;
    float* stateA      = (float*)(w + o);    o += state_bytes;
    float* stateB      = (float*)(w + o);    o += state_bytes;
    __half* wsth       = (__half*)(w + o);   o += wst_bytes;
    rec12* payA        = (rec12*)(w + o);    o += payA_bytes;   // bin-sorted block-major
    rec12* payB        = (rec12*)(w + o);    o += payB_bytes;   // fully nt-sorted
    unsigned* s1addr   = (unsigned*)(w + o); o += s1a_bytes;
    unsigned* binsum   = (unsigned*)(w + o); o += bsum_bytes;
    unsigned* binstart = (unsigned*)(w + o); o += bsum_bytes;
    unsigned* nodestart= (unsigned*)(w + o); o += nst_bytes;
    unsigned* goff     = (unsigned*)(w + o); o += goff_bytes;
    float* gstate      = (float*)(w + o);    o += gst_bytes;
    float4* coords4    = (float4*)(w + o);   o += c4_bytes;

    if (o <= ws_size && NBIN <= NBIN_MAX && N < (1 << 18) && CHUNK <= ECHUNK) {
        // ---- prep + build ----
        coords4_kernel<<<ng, BLK, 0, stream>>>(coords, coords4, N);
        pass1_kernel<<<EB, CTHR, 0, stream>>>(elen, evec, nfrom, nto,
                                              s1addr, payA, E, NBIN);
        colsum_kernel<<<NBIN + 1, 256, 0, stream>>>(s1addr, binsum);
        binstart_kernel<<<1, 256, 0, stream>>>(binsum, binstart, nodestart, NBIN, E);
        pass2_kernel<<<NBIN, CTHR, 0, stream>>>(s1addr, binstart, coords4,
                                                payA, payB, nodestart, NBIN);
        // ---- rounds (sorted 12B payload, high-occupancy 64-node buckets) ----
        round_run_kernel<true><<<NB, BLK, 0, stream>>>(nodestart, payB, Wm, bm,
                                                       wsth, stateB, stateA, N, E);
        wstate_kernel<<<ng, BLK, 0, stream>>>(stateA, Wm, bm, wsth, N);
        round_run_kernel<false><<<NB, BLK, 0, stream>>>(nodestart, payB, Wm, bm,
                                                        wsth, stateA, stateB, N, E);
        wstate_kernel<<<ng, BLK, 0, stream>>>(stateB, Wm, bm, wsth, N);
        round_run_kernel<false><<<NB, BLK, 0, stream>>>(nodestart, payB, Wm, bm,
                                                        wsth, stateB, stateA, N, E);
        // ---- graph phase ----
        hipMemsetAsync(gstate, 0, (size_t)G * SD * sizeof(float), stream);
        goff_kernel<<<ng, BLK, 0, stream>>>(gidx, goff, N, G);
        gsum_kernel<<<(G * SD * 4 + BLK - 1) / BLK, BLK, 0, stream>>>(stateA, goff, gstate, G);
        out_kernel<<<gg, BLK, 0, stream>>>(gstate, Wo, bo, (float*)d_out, G);
    } else {
        // ---- fallback: atomic path ----
        const int eg = (E + BLK - 1) / BLK;
        float* gstateF = (float*)(w + 2 * state_bytes);
        hipMemsetAsync(stateA, 0, state_bytes, stream);
        hipMemsetAsync(gstateF, 0, (size_t)G * SD * sizeof(float), stream);
        edge_kernel_fb<true><<<eg, BLK, 0, stream>>>(coords, elen, evec, Wm, bm,
                                                     nfrom, nto, stateA, stateA, E);
        hipMemcpyAsync(stateB, stateA, state_bytes, hipMemcpyDeviceToDevice, stream);
        edge_kernel_fb<false><<<eg, BLK, 0, stream>>>(coords, elen, evec, Wm, bm,
                                                      nfrom, nto, stateA, stateB, E);
        hipMemcpyAsync(stateA, stateB, state_bytes, hipMemcpyDeviceToDevice, stream);
        edge_kernel_fb<false><<<eg, BLK, 0, stream>>>(coords, elen, evec, Wm, bm,
                                                      nfrom, nto, stateB, stateA, E);
        graph_reduce_fb<<<ng, BLK, 0, stream>>>(stateA, gidx, gstateF, N);
        out_kernel<<<gg, BLK, 0, stream>>>(gstateF, Wo, bo, (float*)d_out, G);
    }
}